// Round 3
// baseline (998.415 us; speedup 1.0000x reference)
//
#include <hip/hip_runtime.h>

// ---------------------------------------------------------------------------
// SchNet-style GNN on MI355X — R3.
// N=50000, E=1600000, H=128, F=64, G=50, L=3, NG=256.
// R3: transposed edge pipeline (weights as A-operand, activations as B).
//  - smear/ssp write LDS in packed b32/b64 (v_perm bf16 pair packing)
//  - epilogue: 4 float4 xj gathers per lane (lane owns one edge)
//  - sort writes fused 16B edata {src,dst,d,C}; k_geom eliminated
//  - agg zeroing folded into node kernels (memsets dropped)
// ---------------------------------------------------------------------------

typedef short bf16x8 __attribute__((ext_vector_type(8)));
typedef float floatx4 __attribute__((ext_vector_type(4)));

#define HCH 128
#define FCH 64
#define GCH 50
#define LN  3

#define MFMA(a, b, c) __builtin_amdgcn_mfma_f32_16x16x32_bf16((a), (b), (c), 0, 0, 0)

__device__ __forceinline__ unsigned short f2bf(float x) {      // RNE (prep/node)
    unsigned int u = __float_as_uint(x);
    unsigned int r = (u + 0x7FFFu + ((u >> 16) & 1u)) >> 16;
    return (unsigned short)r;
}

// pack two floats to bf16 pair (round-half-up) in ~3 VALU ops
__device__ __forceinline__ unsigned pk2bf(float lo, float hi) {
    unsigned ulo = __float_as_uint(lo) + 0x8000u;
    unsigned uhi = __float_as_uint(hi) + 0x8000u;
    return __builtin_amdgcn_perm(uhi, ulo, 0x07060302u);
}

__device__ __forceinline__ float sspf(float x) {
    float t = __expf(-fabsf(x));
    float l = __logf(1.f + t);
    return fmaxf(x, 0.f) + l - 0.69314718056f;
}

// ---------------------------------------------------------------------------
// frag fill: src row-major [Ksrc x F] zero-padded to K; buffer is B-frag for
// normal use AND A-frag for the transposed use (same mapping).
// ---------------------------------------------------------------------------
__device__ __forceinline__ void fill_frag(const float* __restrict__ src,
                                          short* __restrict__ dst,
                                          int K, int F, int Ksrc,
                                          int tid, int nthr)
{
    int kc = K >> 5;
    int total = (F >> 4) * kc * 512;
    for (int i = tid; i < total; i += nthr) {
        int j = i & 7;
        int lane = (i >> 3) & 63;
        int rest = i >> 9;
        int kk = rest % kc;
        int nt = rest / kc;
        int k = kk * 32 + ((lane >> 4) << 3) + j;
        int f = nt * 16 + (lane & 15);
        float v = (k < Ksrc) ? src[k * F + f] : 0.f;
        dst[i] = (short)f2bf(v);
    }
}

__global__ void k_prep(const float* __restrict__ mw1, const float* __restrict__ mw2,
                       const float* __restrict__ l1w, const float* __restrict__ l2w,
                       const float* __restrict__ lw,  const float* __restrict__ ow1,
                       short* __restrict__ mw1p, short* __restrict__ mw2p,
                       short* __restrict__ l1wp, short* __restrict__ l2wp,
                       short* __restrict__ lwp,  short* __restrict__ ow1p)
{
    int tid = blockIdx.x * blockDim.x + threadIdx.x;
    int nthr = gridDim.x * blockDim.x;
    for (int l = 0; l < LN; l++) {
        fill_frag(mw1 + l * GCH * FCH, mw1p + l * 4096, 64, 64, GCH, tid, nthr);
        fill_frag(mw2 + l * FCH * FCH, mw2p + l * 4096, 64, 64, 64, tid, nthr);
        fill_frag(l1w + l * HCH * FCH, l1wp + l * 8192, 128, 64, 128, tid, nthr);
        fill_frag(l2w + l * FCH * HCH, l2wp + l * 8192, 64, 128, 64, tid, nthr);
        fill_frag(lw  + l * HCH * HCH, lwp  + l * 16384, 128, 128, 128, tid, nthr);
    }
    fill_frag(ow1, ow1p, 128, 64, 128, tid, nthr);
}

// ---------------------------------------------------------------------------
// Counting sort by dst: hist -> scan -> scatter (fused geometry, 16B payload)
// ---------------------------------------------------------------------------
__global__ void k_hist(const int* __restrict__ ei, int* __restrict__ hist, int E)
{
    int e = blockIdx.x * blockDim.x + threadIdx.x;
    if (e < E) atomicAdd(&hist[ei[E + e]], 1);
}

__global__ __launch_bounds__(1024) void k_scan(const int* __restrict__ hist,
                                               int* __restrict__ cursor, int N)
{
    __shared__ int part[1024];
    int t = threadIdx.x;
    int b = t * 49;
    int s = 0;
    for (int i = 0; i < 49; i++) { int idx = b + i; if (idx < N) s += hist[idx]; }
    part[t] = s;
    __syncthreads();
    for (int off = 1; off < 1024; off <<= 1) {
        int v = (t >= off) ? part[t - off] : 0;
        __syncthreads();
        part[t] += v;
        __syncthreads();
    }
    int run = (t > 0) ? part[t - 1] : 0;
    for (int i = 0; i < 49; i++) {
        int idx = b + i;
        if (idx < N) { cursor[idx] = run; run += hist[idx]; }
    }
}

__global__ void k_scatter2(const int* __restrict__ ei, const float* __restrict__ pos,
                           int* __restrict__ cursor, int4* __restrict__ edata, int E)
{
    int e = blockIdx.x * blockDim.x + threadIdx.x;
    if (e >= E) return;
    int s = ei[e], d2 = ei[E + e];
    float dx = pos[s * 3 + 0] - pos[d2 * 3 + 0];
    float dy = pos[s * 3 + 1] - pos[d2 * 3 + 1];
    float dz = pos[s * 3 + 2] - pos[d2 * 3 + 2];
    float dist = sqrtf(dx * dx + dy * dy + dz * dz);
    float C = 0.5f * (__cosf(dist * 0.31415926535897932f) + 1.f);
    int p = atomicAdd(&cursor[d2], 1);
    edata[p] = make_int4(s, d2, __float_as_int(dist), __float_as_int(C));
}

// ---------------------------------------------------------------------------
// k_node0: h = emb[z]; xj = h @ l1w[0]; agg = 0
// ---------------------------------------------------------------------------
__global__ __launch_bounds__(256) void k_node0(const int* __restrict__ z,
    const float* __restrict__ emb, const short* __restrict__ l1wp0,
    float* __restrict__ h, float* __restrict__ xj, float* __restrict__ agg, int N)
{
    __shared__ __align__(16) short A3[8192];
    __shared__ int zL[64];
    int t = threadIdx.x, lane = t & 63, w = t >> 6;
    int n0 = blockIdx.x * 64;
    if (t < 64) { int n = n0 + t; zL[t] = (n < N) ? z[n] : 0; }
    __syncthreads();
    // zero agg for layer 0
    for (int i = t; i < 4096; i += 256) {
        int n = n0 + (i >> 6);
        if (n < N) agg[(size_t)n * FCH + (i & 63)] = 0.f;
    }
#pragma unroll
    for (int m = 0; m < 16; m++) {
        int ii = lane + 64 * m;
        int rloc = ii >> 6;
        int k0 = (ii & 63) * 2;
        int n = n0 + w * 16 + rloc;
        float2 v = make_float2(0.f, 0.f);
        if (n < N) {
            v = *(const float2*)(&emb[(size_t)zL[w * 16 + rloc] * HCH + k0]);
            *(float2*)(&h[(size_t)n * HCH + k0]) = v;
        }
        unsigned pk = pk2bf(v.x, v.y);
        int si = w * 2048 + (k0 >> 5) * 512 + (rloc + 16 * ((k0 >> 3) & 3)) * 8 + (k0 & 7);
        *(unsigned*)(&A3[si]) = pk;
    }
    int quad = lane >> 4, col = lane & 15;
    const bf16x8* B = (const bf16x8*)l1wp0;
    bf16x8 af[4];
#pragma unroll
    for (int kk = 0; kk < 4; kk++)
        af[kk] = *(const bf16x8*)(&A3[w * 2048 + kk * 512 + lane * 8]);
#pragma unroll
    for (int nt = 0; nt < 4; nt++) {
        floatx4 c = {0.f, 0.f, 0.f, 0.f};
#pragma unroll
        for (int kk = 0; kk < 4; kk++) c = MFMA(af[kk], B[(nt * 4 + kk) * 64 + lane], c);
        int f = nt * 16 + col;
#pragma unroll
        for (int reg = 0; reg < 4; reg++) {
            int n = n0 + w * 16 + quad * 4 + reg;
            if (n < N) xj[(size_t)n * FCH + f] = c[reg];
        }
    }
}

// ---------------------------------------------------------------------------
// Edge kernel R3 (transposed): t1^T = mw1^T @ ea^T ; W^T = mw2^T @ ssp(t1)^T
// 64 edges/block, 4 waves; lane owns edge e=lane&15 in epilogue.
// ---------------------------------------------------------------------------
__global__ __launch_bounds__(256) void k_edge(
    const int4* __restrict__ edata, const float* __restrict__ xj,
    const short* __restrict__ mw1p, const short* __restrict__ mw2p,
    const float* __restrict__ mb1, const float* __restrict__ mb2,
    float* __restrict__ agg, int layer, int E)
{
    __shared__ __align__(16) short EA[4096];   // ea^T  B-frag, per-wave 1024
    __shared__ __align__(16) short T1[4096];   // ssp^T B-frag, per-wave 1024
    __shared__ __align__(16) float M[64 * 68];
    __shared__ float dL[64], cL[64];
    __shared__ int sL[64], tL[64];

    int t = threadIdx.x;
    int e0 = blockIdx.x * 64;
    if (t < 64) {
        int eg = e0 + t;
        int4 ed = make_int4(0, -1, 0, 0);
        if (eg < E) ed = edata[eg];
        sL[t] = ed.x; tL[t] = ed.y;
        dL[t] = __int_as_float(ed.z);
        cL[t] = __int_as_float(ed.w);
    }
    __syncthreads();

    int lane = t & 63, w = t >> 6;
    int eL_ = lane & 15;
    int kb  = lane >> 4;

    // ---- Gaussian smear -> EA (B-frag: element(g,e) at
    //      (g>>5)*512 + (e+16*((g>>3)&3))*8 + (g&7)). Lane: row e, g in
    //      [kb*16, kb*16+16). g>=50 gives tiny values hitting zero weights.
    {
        const float step = 10.f / 49.f;
        const float coeff = -0.5f / (step * step);
        float d = dL[w * 16 + eL_];
        float dk = d - (float)(kb * 16) * step;
        short* R = &EA[w * 1024];
#pragma unroll
        for (int p = 0; p < 8; p++) {
            float u0 = dk - (float)(2 * p) * step;
            float u1 = dk - (float)(2 * p + 1) * step;
            float g0 = __expf(coeff * u0 * u0);
            float g1 = __expf(coeff * u1 * u1);
            int g = kb * 16 + 2 * p;
            int si = (g >> 5) * 512 + (eL_ + 16 * ((g >> 3) & 3)) * 8 + (g & 7);
            *(unsigned*)(&R[si]) = pk2bf(g0, g1);
        }
    }
    // intra-wave LDS producer/consumer: program order suffices, no barrier

    int quad = lane >> 4, col = lane & 15;
    const bf16x8* W1 = (const bf16x8*)(mw1p + layer * 4096);
    const bf16x8* W2 = (const bf16x8*)(mw2p + layer * 4096);

    bf16x8 b0 = *(const bf16x8*)(&EA[w * 1024 + lane * 8]);
    bf16x8 b1 = *(const bf16x8*)(&EA[w * 1024 + 512 + lane * 8]);

    // GEMM1': D[f1][e] ; lane holds e=col, f1 = mt*16+quad*4+r
#pragma unroll
    for (int mt = 0; mt < 4; mt++) {
        float4 bias = *(const float4*)(&mb1[layer * FCH + mt * 16 + quad * 4]);
        floatx4 c = {bias.x, bias.y, bias.z, bias.w};
        c = MFMA(W1[(mt * 2 + 0) * 64 + lane], b0, c);
        c = MFMA(W1[(mt * 2 + 1) * 64 + lane], b1, c);
        // ssp -> T1 (B-frag for GEMM2'): 4 consecutive shorts
        unsigned lo = pk2bf(sspf(c[0]), sspf(c[1]));
        unsigned hi = pk2bf(sspf(c[2]), sspf(c[3]));
        int f1b = mt * 16 + quad * 4;
        int si = (f1b >> 5) * 512 + (col + 16 * ((f1b >> 3) & 3)) * 8 + (f1b & 7);
        *(uint2*)(&T1[w * 1024 + si]) = make_uint2(lo, hi);
    }

    bf16x8 p0 = *(const bf16x8*)(&T1[w * 1024 + lane * 8]);
    bf16x8 p1 = *(const bf16x8*)(&T1[w * 1024 + 512 + lane * 8]);

    float cc = cL[w * 16 + col];
    const float* xrow = xj + (size_t)sL[w * 16 + col] * FCH;

    // GEMM2' + epilogue: msg[e][f] = W^T[f][e] * C * xj[src][f]
#pragma unroll
    for (int mt = 0; mt < 4; mt++) {
        float4 bias = *(const float4*)(&mb2[layer * FCH + mt * 16 + quad * 4]);
        floatx4 c = {bias.x, bias.y, bias.z, bias.w};
        c = MFMA(W2[(mt * 2 + 0) * 64 + lane], p0, c);
        c = MFMA(W2[(mt * 2 + 1) * 64 + lane], p1, c);
        float4 xv = *(const float4*)(&xrow[mt * 16 + quad * 4]);
        float4 m;
        m.x = c[0] * cc * xv.x;
        m.y = c[1] * cc * xv.y;
        m.z = c[2] * cc * xv.z;
        m.w = c[3] * cc * xv.w;
        *(float4*)(&M[(w * 16 + col) * 68 + mt * 16 + quad * 4]) = m;
    }

    // segmented reduce over the wave's 16 sorted rows; lane = f
    {
        int f = lane;
        int base = w * 16;
        float a = 0.f;
        int cur = tL[base];
#pragma unroll
        for (int i = 0; i < 16; i++) {
            int d = tL[base + i];
            if (d != cur) {
                if (cur >= 0) unsafeAtomicAdd(&agg[(size_t)cur * FCH + f], a);
                a = 0.f; cur = d;
            }
            a += M[(base + i) * 68 + f];
        }
        if (cur >= 0) unsafeAtomicAdd(&agg[(size_t)cur * FCH + f], a);
    }
}

// ---------------------------------------------------------------------------
// Node update (layers 0,1): x=ssp(agg@l2w+b); x=x@lw+b; h+=x; xj=h@l1w[l+1];
// agg=0 for next layer. 64 nodes/block, 4 waves, barrier-free.
// ---------------------------------------------------------------------------
__global__ __launch_bounds__(256) void k_update(
    float* __restrict__ agg, const short* __restrict__ l2wp,
    const float* __restrict__ l2b, const short* __restrict__ lwp,
    const float* __restrict__ lb,  const short* __restrict__ l1wp_next,
    float* __restrict__ h, float* __restrict__ xj, int layer, int N)
{
    __shared__ __align__(16) short Aa[4096];
    __shared__ __align__(16) short A2[8192];
    __shared__ __align__(16) short A3[8192];
    int t = threadIdx.x, lane = t & 63, w = t >> 6;
    int n0 = blockIdx.x * 64;
#pragma unroll
    for (int m = 0; m < 8; m++) {
        int ii = lane + 64 * m;
        int rloc = ii >> 5;
        int k0 = (ii & 31) * 2;
        int n = n0 + w * 16 + rloc;
        float2 v = make_float2(0.f, 0.f);
        if (n < N) v = *(const float2*)(&agg[(size_t)n * FCH + k0]);
        unsigned pk = pk2bf(v.x, v.y);
        int si = w * 1024 + (k0 >> 5) * 512 + (rloc + 16 * ((k0 >> 3) & 3)) * 8 + (k0 & 7);
        *(unsigned*)(&Aa[si]) = pk;
    }
    // zero this wave's agg rows for the next layer (loads already consumed)
#pragma unroll
    for (int i = 0; i < 16; i++) {
        int n = n0 + w * 16 + i;
        if (n < N) agg[(size_t)n * FCH + lane] = 0.f;
    }
    int quad = lane >> 4, col = lane & 15;
    const bf16x8* Bl2 = (const bf16x8*)(l2wp + layer * 8192);
    const bf16x8* Blw = (const bf16x8*)(lwp + layer * 16384);
    const bf16x8* Bl1 = (const bf16x8*)l1wp_next;

    bf16x8 a0 = *(const bf16x8*)(&Aa[w * 1024 + lane * 8]);
    bf16x8 a1 = *(const bf16x8*)(&Aa[w * 1024 + 512 + lane * 8]);
#pragma unroll
    for (int nt = 0; nt < 8; nt++) {
        float bias = l2b[layer * HCH + nt * 16 + col];
        floatx4 c = {bias, bias, bias, bias};
        c = MFMA(a0, Bl2[(nt * 2 + 0) * 64 + lane], c);
        c = MFMA(a1, Bl2[(nt * 2 + 1) * 64 + lane], c);
        int f = nt * 16 + col;
        int si0 = w * 2048 + (f >> 5) * 512 + (16 * ((f >> 3) & 3)) * 8 + (f & 7);
#pragma unroll
        for (int reg = 0; reg < 4; reg++)
            A2[si0 + (quad * 4 + reg) * 8] = (short)f2bf(sspf(c[reg]));
    }
    bf16x8 af[4];
#pragma unroll
    for (int kk = 0; kk < 4; kk++)
        af[kk] = *(const bf16x8*)(&A2[w * 2048 + kk * 512 + lane * 8]);
#pragma unroll
    for (int nt = 0; nt < 8; nt++) {
        float bias = lb[layer * HCH + nt * 16 + col];
        floatx4 c = {bias, bias, bias, bias};
#pragma unroll
        for (int kk = 0; kk < 4; kk++) c = MFMA(af[kk], Blw[(nt * 4 + kk) * 64 + lane], c);
        int f = nt * 16 + col;
        int si0 = w * 2048 + (f >> 5) * 512 + (16 * ((f >> 3) & 3)) * 8 + (f & 7);
#pragma unroll
        for (int reg = 0; reg < 4; reg++) {
            int n = n0 + w * 16 + quad * 4 + reg;
            float hv = 0.f;
            if (n < N) {
                hv = h[(size_t)n * HCH + f] + c[reg];
                h[(size_t)n * HCH + f] = hv;
            }
            A3[si0 + (quad * 4 + reg) * 8] = (short)f2bf(hv);
        }
    }
#pragma unroll
    for (int kk = 0; kk < 4; kk++)
        af[kk] = *(const bf16x8*)(&A3[w * 2048 + kk * 512 + lane * 8]);
#pragma unroll
    for (int nt = 0; nt < 4; nt++) {
        floatx4 c = {0.f, 0.f, 0.f, 0.f};
#pragma unroll
        for (int kk = 0; kk < 4; kk++) c = MFMA(af[kk], Bl1[(nt * 4 + kk) * 64 + lane], c);
        int f = nt * 16 + col;
#pragma unroll
        for (int reg = 0; reg < 4; reg++) {
            int n = n0 + w * 16 + quad * 4 + reg;
            if (n < N) xj[(size_t)n * FCH + f] = c[reg];
        }
    }
}

// ---------------------------------------------------------------------------
// Final layer: node update + output MLP + per-graph atomic readout
// ---------------------------------------------------------------------------
__global__ __launch_bounds__(256) void k_final(
    const float* __restrict__ agg, const short* __restrict__ l2wp,
    const float* __restrict__ l2b, const short* __restrict__ lwp,
    const float* __restrict__ lb,  const short* __restrict__ ow1p,
    const float* __restrict__ ob1, const float* __restrict__ ow2,
    const float* __restrict__ ob2, const int* __restrict__ batch,
    const float* __restrict__ h, float* __restrict__ out, int layer, int N)
{
    __shared__ __align__(16) short Aa[4096];
    __shared__ __align__(16) short A2[8192];
    __shared__ __align__(16) short A3[8192];
    __shared__ float R[64 * 17];
    int t = threadIdx.x, lane = t & 63, w = t >> 6;
    int n0 = blockIdx.x * 64;
#pragma unroll
    for (int m = 0; m < 8; m++) {
        int ii = lane + 64 * m;
        int rloc = ii >> 5;
        int k0 = (ii & 31) * 2;
        int n = n0 + w * 16 + rloc;
        float2 v = make_float2(0.f, 0.f);
        if (n < N) v = *(const float2*)(&agg[(size_t)n * FCH + k0]);
        unsigned pk = pk2bf(v.x, v.y);
        int si = w * 1024 + (k0 >> 5) * 512 + (rloc + 16 * ((k0 >> 3) & 3)) * 8 + (k0 & 7);
        *(unsigned*)(&Aa[si]) = pk;
    }
    int quad = lane >> 4, col = lane & 15;
    const bf16x8* Bl2 = (const bf16x8*)(l2wp + layer * 8192);
    const bf16x8* Blw = (const bf16x8*)(lwp + layer * 16384);
    const bf16x8* Bow = (const bf16x8*)ow1p;

    bf16x8 a0 = *(const bf16x8*)(&Aa[w * 1024 + lane * 8]);
    bf16x8 a1 = *(const bf16x8*)(&Aa[w * 1024 + 512 + lane * 8]);
#pragma unroll
    for (int nt = 0; nt < 8; nt++) {
        float bias = l2b[layer * HCH + nt * 16 + col];
        floatx4 c = {bias, bias, bias, bias};
        c = MFMA(a0, Bl2[(nt * 2 + 0) * 64 + lane], c);
        c = MFMA(a1, Bl2[(nt * 2 + 1) * 64 + lane], c);
        int f = nt * 16 + col;
        int si0 = w * 2048 + (f >> 5) * 512 + (16 * ((f >> 3) & 3)) * 8 + (f & 7);
#pragma unroll
        for (int reg = 0; reg < 4; reg++)
            A2[si0 + (quad * 4 + reg) * 8] = (short)f2bf(sspf(c[reg]));
    }
    bf16x8 af[4];
#pragma unroll
    for (int kk = 0; kk < 4; kk++)
        af[kk] = *(const bf16x8*)(&A2[w * 2048 + kk * 512 + lane * 8]);
#pragma unroll
    for (int nt = 0; nt < 8; nt++) {
        float bias = lb[layer * HCH + nt * 16 + col];
        floatx4 c = {bias, bias, bias, bias};
#pragma unroll
        for (int kk = 0; kk < 4; kk++) c = MFMA(af[kk], Blw[(nt * 4 + kk) * 64 + lane], c);
        int f = nt * 16 + col;
        int si0 = w * 2048 + (f >> 5) * 512 + (16 * ((f >> 3) & 3)) * 8 + (f & 7);
#pragma unroll
        for (int reg = 0; reg < 4; reg++) {
            int n = n0 + w * 16 + quad * 4 + reg;
            float hv = 0.f;
            if (n < N) hv = h[(size_t)n * HCH + f] + c[reg];
            A3[si0 + (quad * 4 + reg) * 8] = (short)f2bf(hv);
        }
    }
#pragma unroll
    for (int kk = 0; kk < 4; kk++)
        af[kk] = *(const bf16x8*)(&A3[w * 2048 + kk * 512 + lane * 8]);
    float p[4] = {0.f, 0.f, 0.f, 0.f};
#pragma unroll
    for (int nt = 0; nt < 4; nt++) {
        float bias = ob1[nt * 16 + col];
        floatx4 c = {bias, bias, bias, bias};
#pragma unroll
        for (int kk = 0; kk < 4; kk++) c = MFMA(af[kk], Bow[(nt * 4 + kk) * 64 + lane], c);
        float w2 = ow2[nt * 16 + col];
#pragma unroll
        for (int reg = 0; reg < 4; reg++) p[reg] += sspf(c[reg]) * w2;
    }
#pragma unroll
    for (int reg = 0; reg < 4; reg++)
        R[(w * 16 + quad * 4 + reg) * 17 + col] = p[reg];
    __syncthreads();
    if (t < 64) {
        int n = n0 + t;
        if (n < N) {
            float v = ob2[0];
#pragma unroll
            for (int c2 = 0; c2 < 16; c2++) v += R[t * 17 + c2];
            unsafeAtomicAdd(&out[batch[n]], v);
        }
    }
}

// ---------------------------------------------------------------------------
extern "C" void kernel_launch(void* const* d_in, const int* in_sizes, int n_in,
                              void* d_out, int out_size, void* d_ws, size_t ws_size,
                              hipStream_t stream)
{
    const int*   z    = (const int*)d_in[0];
    const float* pos  = (const float*)d_in[1];
    const int*   batc = (const int*)d_in[2];
    const int*   ei   = (const int*)d_in[3];
    const float* emb  = (const float*)d_in[4];
    const float* mw1  = (const float*)d_in[5];
    const float* mb1  = (const float*)d_in[6];
    const float* mw2  = (const float*)d_in[7];
    const float* mb2  = (const float*)d_in[8];
    const float* l1w  = (const float*)d_in[9];
    const float* l2w  = (const float*)d_in[10];
    const float* l2b  = (const float*)d_in[11];
    const float* lw   = (const float*)d_in[12];
    const float* lb   = (const float*)d_in[13];
    const float* ow1  = (const float*)d_in[14];
    const float* ob1  = (const float*)d_in[15];
    const float* ow2  = (const float*)d_in[16];
    const float* ob2  = (const float*)d_in[17];
    float* out = (float*)d_out;

    int N = in_sizes[0];
    int E = in_sizes[3] / 2;

    char* ws = (char*)d_ws;
    size_t off = 0;
    auto alloc = [&](size_t bytes) {
        void* p = ws + off;
        off = (off + bytes + 255) & ~(size_t)255;
        return p;
    };
    float* h      = (float*)alloc((size_t)N * HCH * 4);
    float* xj     = (float*)alloc((size_t)N * FCH * 4);
    float* agg    = (float*)alloc((size_t)N * FCH * 4);
    int4*  edata  = (int4*)alloc((size_t)E * 16);
    int*   hist   = (int*)alloc((size_t)N * 4);
    int*   cursor = (int*)alloc((size_t)N * 4);
    short* mw1p   = (short*)alloc(LN * 4096 * 2);
    short* mw2p   = (short*)alloc(LN * 4096 * 2);
    short* l1wp   = (short*)alloc(LN * 8192 * 2);
    short* l2wp   = (short*)alloc(LN * 8192 * 2);
    short* lwp    = (short*)alloc(LN * 16384 * 2);
    short* ow1p   = (short*)alloc(8192 * 2);

    int EB256 = (E + 255) / 256;
    int NB = (N + 63) / 64;
    int EB = (E + 63) / 64;

    k_prep<<<64, 256, 0, stream>>>(mw1, mw2, l1w, l2w, lw, ow1,
                                   mw1p, mw2p, l1wp, l2wp, lwp, ow1p);
    hipMemsetAsync(hist, 0, (size_t)N * 4, stream);
    k_hist<<<EB256, 256, 0, stream>>>(ei, hist, E);
    k_scan<<<1, 1024, 0, stream>>>(hist, cursor, N);
    k_scatter2<<<EB256, 256, 0, stream>>>(ei, pos, cursor, edata, E);
    hipMemsetAsync(out, 0, (size_t)out_size * sizeof(float), stream);

    k_node0<<<NB, 256, 0, stream>>>(z, emb, l1wp, h, xj, agg, N);
    for (int l = 0; l < LN; l++) {
        k_edge<<<EB, 256, 0, stream>>>(edata, xj, mw1p, mw2p, mb1, mb2,
                                       agg, l, E);
        if (l < LN - 1) {
            k_update<<<NB, 256, 0, stream>>>(agg, l2wp, l2b, lwp, lb,
                                             l1wp + (l + 1) * 8192, h, xj, l, N);
        } else {
            k_final<<<NB, 256, 0, stream>>>(agg, l2wp, l2b, lwp, lb, ow1p,
                                            ob1, ow2, ob2, batc, h, out, l, N);
        }
    }
}